// Round 1
// baseline (240.519 us; speedup 1.0000x reference)
//
#include <hip/hip_runtime.h>
#include <math.h>

// Bitonic network layer tables: l = blk*(blk+1)/2 + lay, m = 2^(blk-lay)
static constexpr int LLB[36] = {
  0,
  1,0,
  2,1,0,
  3,2,1,0,
  4,3,2,1,0,
  5,4,3,2,1,0,
  6,5,4,3,2,1,0,
  7,6,5,4,3,2,1,0
};
static constexpr int LBLK[36] = {
  0,
  1,1,
  2,2,2,
  3,3,3,3,
  4,4,4,4,4,
  5,5,5,5,5,5,
  6,6,6,6,6,6,6,
  7,7,7,7,7,7,7,7
};

// ---------------------------------------------------------------------------
// Kernel A: coefficient generation.
// u[b][l][k] = d ? 1-alpha : alpha,  alpha = atan(10*(v[q]-v[p]))/pi + 0.5
// Pair k of layer l: p = ((k>>lb)<<(lb+1)) | (k & (m-1)), q = p+m,
// d = (p >> (blk+1)) & 1.  Both pair outputs use the SAME u:
//   new[p] = u*x[p] + (1-u)*x[q];  new[q] = u*x[q] + (1-u)*x[p]
// ---------------------------------------------------------------------------
__global__ __launch_bounds__(128) void k_ugen(const float* __restrict__ vec,
                                              float* __restrict__ U) {
  const int b = blockIdx.x;
  const int k = threadIdx.x;            // 0..127 = pair index
  const float* v = vec + b * 256;
  float* ub = U + (size_t)b * 4608;
  #pragma unroll
  for (int l = 0; l < 36; ++l) {
    const int lb  = LLB[l];
    const int blk = LBLK[l];
    const int m = 1 << lb;
    const int p = ((k >> lb) << (lb + 1)) | (k & (m - 1));
    const int q = p + m;
    const int d = (p >> (blk + 1)) & 1;
    const float alpha =
        atanf(10.0f * (v[q] - v[p])) * 0.3183098861837907f + 0.5f;
    ub[l * 128 + k] = d ? (1.0f - alpha) : alpha;
  }
}

// ---------------------------------------------------------------------------
// Kernel B: blocks 0..5 (layers 0..20, all m<=32).  Row e_i stays inside its
// aligned 64-column group, so each thread = one row, 64 registers, fully
// in-register butterfly.  u addresses are wave-uniform (g = tid>>6).
// Writes compact 64-float rows to staging.
// ---------------------------------------------------------------------------
__global__ __launch_bounds__(256) void k_phase1(const float* __restrict__ U,
                                                float* __restrict__ staged) {
  const int b = blockIdx.x;
  const int i = threadIdx.x;            // row 0..255
  const int g = i >> 6;                 // 64-col group (wave-uniform)
  const int il = i & 63;
  float r[64];
  #pragma unroll
  for (int j = 0; j < 64; ++j) r[j] = (j == il) ? 1.0f : 0.0f;

  const int ubase = __builtin_amdgcn_readfirstlane(b * 4608 + 32 * g);
  #pragma unroll
  for (int l = 0; l < 21; ++l) {
    const int lb = LLB[l];
    const int m = 1 << lb;
    const float* ul = U + ubase + l * 128;
    #pragma unroll
    for (int kl = 0; kl < 32; ++kl) {
      const int p = ((kl >> lb) << (lb + 1)) | (kl & (m - 1));
      const int q = p + m;
      const float u = ul[kl];
      const float t  = r[p] - r[q];
      const float np = fmaf(u, t, r[q]);    // u*p + (1-u)*q
      const float nq = fmaf(-u, t, r[p]);   // u*q + (1-u)*p
      r[p] = np;
      r[q] = nq;
    }
  }
  float* op = staged + ((size_t)b * 256 + i) * 64;
  #pragma unroll
  for (int t = 0; t < 16; ++t)
    *(float4*)(op + 4 * t) =
        make_float4(r[4*t], r[4*t+1], r[4*t+2], r[4*t+3]);
}

// ---------------------------------------------------------------------------
// Kernel C: blocks 6..7 (layers 21..35).  Block = (b, rowgroup g of 64 rows).
// Thread = (chunk c of 64 cols, row r), tid = c*64 + r  => each wave is one
// chunk, u addresses wave-uniform.  Two LDS exchanges (m=128, m=64@blk7) with
// lane-contiguous b128 pattern; everything else in registers.
// ---------------------------------------------------------------------------
__global__ __launch_bounds__(256) void k_phase23(const float* __restrict__ U,
                                                 const float* __restrict__ staged,
                                                 float* __restrict__ out) {
  const int bg = blockIdx.x;
  const int b = bg >> 2;
  const int g = bg & 3;
  const int c  = threadIdx.x >> 6;      // chunk 0..3 (== wave id)
  const int rr = threadIdx.x & 63;      // row within group
  const int i = g * 64 + rr;
  __shared__ float4 ex4[4096];          // [c*16+t][rr], 64 KB
  float y[64];

  const int ub = __builtin_amdgcn_readfirstlane(b * 4608);

  // ---- l=21: blk6, m=64.  Incoming support = cols [64g,64g+64); exactly one
  // chunk of each pair is nonzero, so new = staged * (u or 1-u), or 0.
  {
    const int ap = g >> 1;              // 128-region
    if ((c >> 1) == ap) {
      const float* u21 = U + ub + 21 * 128 + 64 * ap;
      const bool sm = ((c & 1) == (g & 1));   // my side == nonzero side
      const float* srp = staged + ((size_t)b * 256 + i) * 64;
      #pragma unroll
      for (int t = 0; t < 16; ++t) {
        const float4 s4 = *(const float4*)(srp + 4 * t);
        const float u0 = u21[4*t+0], u1 = u21[4*t+1];
        const float u2 = u21[4*t+2], u3 = u21[4*t+3];
        y[4*t+0] = s4.x * (sm ? u0 : 1.0f - u0);
        y[4*t+1] = s4.y * (sm ? u1 : 1.0f - u1);
        y[4*t+2] = s4.z * (sm ? u2 : 1.0f - u2);
        y[4*t+3] = s4.w * (sm ? u3 : 1.0f - u3);
      }
    } else {
      #pragma unroll
      for (int j = 0; j < 64; ++j) y[j] = 0.0f;
    }
  }

  const int cb = __builtin_amdgcn_readfirstlane(32 * c);

  // ---- blk6 in-register layers l=22..27 (m=32..1), pairs k in [32c,32c+32)
  #pragma unroll
  for (int l = 22; l < 28; ++l) {
    const int lb = LLB[l];
    const int m = 1 << lb;
    const float* ul = U + ub + l * 128 + cb;
    #pragma unroll
    for (int kl = 0; kl < 32; ++kl) {
      const int p = ((kl >> lb) << (lb + 1)) | (kl & (m - 1));
      const int q = p + m;
      const float u = ul[kl];
      const float t  = y[p] - y[q];
      const float np = fmaf(u, t, y[q]);
      const float nq = fmaf(-u, t, y[p]);
      y[p] = np;
      y[q] = nq;
    }
  }

  // ---- exchange 1 + l=28 (blk7, m=128): partner chunk c^2
  #pragma unroll
  for (int t = 0; t < 16; ++t)
    ex4[(c * 16 + t) * 64 + rr] =
        make_float4(y[4*t], y[4*t+1], y[4*t+2], y[4*t+3]);
  __syncthreads();
  {
    const int pc = c ^ 2;
    const float* u28 = U + ub + 28 * 128 + 64 * (c & 1);
    #pragma unroll
    for (int t = 0; t < 16; ++t) {
      const float4 p4 = ex4[(pc * 16 + t) * 64 + rr];
      const float u0 = u28[4*t+0], u1 = u28[4*t+1];
      const float u2 = u28[4*t+2], u3 = u28[4*t+3];
      y[4*t+0] = fmaf(u0, y[4*t+0] - p4.x, p4.x);
      y[4*t+1] = fmaf(u1, y[4*t+1] - p4.y, p4.y);
      y[4*t+2] = fmaf(u2, y[4*t+2] - p4.z, p4.z);
      y[4*t+3] = fmaf(u3, y[4*t+3] - p4.w, p4.w);
    }
  }
  __syncthreads();

  // ---- exchange 2 + l=29 (blk7, m=64): partner chunk c^1
  #pragma unroll
  for (int t = 0; t < 16; ++t)
    ex4[(c * 16 + t) * 64 + rr] =
        make_float4(y[4*t], y[4*t+1], y[4*t+2], y[4*t+3]);
  __syncthreads();
  {
    const int pc = c ^ 1;
    const float* u29 = U + ub + 29 * 128 + 64 * (c >> 1);
    #pragma unroll
    for (int t = 0; t < 16; ++t) {
      const float4 p4 = ex4[(pc * 16 + t) * 64 + rr];
      const float u0 = u29[4*t+0], u1 = u29[4*t+1];
      const float u2 = u29[4*t+2], u3 = u29[4*t+3];
      y[4*t+0] = fmaf(u0, y[4*t+0] - p4.x, p4.x);
      y[4*t+1] = fmaf(u1, y[4*t+1] - p4.y, p4.y);
      y[4*t+2] = fmaf(u2, y[4*t+2] - p4.z, p4.z);
      y[4*t+3] = fmaf(u3, y[4*t+3] - p4.w, p4.w);
    }
  }

  // ---- blk7 in-register layers l=30..35 (m=32..1)
  #pragma unroll
  for (int l = 30; l < 36; ++l) {
    const int lb = LLB[l];
    const int m = 1 << lb;
    const float* ul = U + ub + l * 128 + cb;
    #pragma unroll
    for (int kl = 0; kl < 32; ++kl) {
      const int p = ((kl >> lb) << (lb + 1)) | (kl & (m - 1));
      const int q = p + m;
      const float u = ul[kl];
      const float t  = y[p] - y[q];
      const float np = fmaf(u, t, y[q]);
      const float nq = fmaf(-u, t, y[p]);
      y[p] = np;
      y[q] = nq;
    }
  }

  // ---- store
  float* op = out + ((size_t)(b * 256 + i)) * 256 + 64 * c;
  #pragma unroll
  for (int t = 0; t < 16; ++t)
    *(float4*)(op + 4 * t) =
        make_float4(y[4*t], y[4*t+1], y[4*t+2], y[4*t+3]);
}

// ---------------------------------------------------------------------------
extern "C" void kernel_launch(void* const* d_in, const int* in_sizes, int n_in,
                              void* d_out, int out_size, void* d_ws, size_t ws_size,
                              hipStream_t stream) {
  const float* vec = (const float*)d_in[0];   // vectors (512,256) f32
  float* out = (float*)d_out;                 // (512,256,256) f32
  float* U = (float*)d_ws;                    // 512*36*128 f32 = 9.4 MB
  float* staged = U + (size_t)512 * 4608;     // 512*256*64 f32 = 33.5 MB

  hipLaunchKernelGGL(k_ugen,    dim3(512),  dim3(128), 0, stream, vec, U);
  hipLaunchKernelGGL(k_phase1,  dim3(512),  dim3(256), 0, stream, U, staged);
  hipLaunchKernelGGL(k_phase23, dim3(2048), dim3(256), 0, stream, U, staged, out);
}

// Round 2
// 225.386 us; speedup vs baseline: 1.0671x; 1.0671x over previous
//
#include <hip/hip_runtime.h>
#include <math.h>

typedef float vf4 __attribute__((ext_vector_type(4)));

// Bitonic network layer tables: l = blk*(blk+1)/2 + lay, m = 2^(blk-lay)
static constexpr int LLB[36] = {
  0,
  1,0,
  2,1,0,
  3,2,1,0,
  4,3,2,1,0,
  5,4,3,2,1,0,
  6,5,4,3,2,1,0,
  7,6,5,4,3,2,1,0
};
static constexpr int LBLK[36] = {
  0,
  1,1,
  2,2,2,
  3,3,3,3,
  4,4,4,4,4,
  5,5,5,5,5,5,
  6,6,6,6,6,6,6,
  7,7,7,7,7,7,7,7
};

// ---------------------------------------------------------------------------
// Kernel A: coefficient generation.
// u[b][l][k] = d ? 1-alpha : alpha,  alpha = atan(10*(v[q]-v[p]))/pi + 0.5
// Both pair outputs use the SAME u:
//   new[p] = u*x[p] + (1-u)*x[q];  new[q] = u*x[q] + (1-u)*x[p]
// ---------------------------------------------------------------------------
__global__ __launch_bounds__(128) void k_ugen(const float* __restrict__ vec,
                                              float* __restrict__ U) {
  const int b = blockIdx.x;
  const int k = threadIdx.x;            // 0..127 = pair index
  const float* v = vec + b * 256;
  float* ub = U + (size_t)b * 4608;
  #pragma unroll
  for (int l = 0; l < 36; ++l) {
    const int lb  = LLB[l];
    const int blk = LBLK[l];
    const int m = 1 << lb;
    const int p = ((k >> lb) << (lb + 1)) | (k & (m - 1));
    const int q = p + m;
    const int d = (p >> (blk + 1)) & 1;
    const float alpha =
        atanf(10.0f * (v[q] - v[p])) * 0.3183098861837907f + 0.5f;
    ub[l * 128 + k] = d ? (1.0f - alpha) : alpha;
  }
}

// ---------------------------------------------------------------------------
// Kernel B: blocks 0..5 (layers 0..20, all m<=32).  Row e_i stays inside its
// aligned 64-column group, so each thread = one row, 64 registers, fully
// in-register butterfly.  u addresses are wave-uniform (g = tid>>6).
// ---------------------------------------------------------------------------
__global__ __launch_bounds__(256) void k_phase1(const float* __restrict__ U,
                                                float* __restrict__ staged) {
  const int b = blockIdx.x;
  const int i = threadIdx.x;            // row 0..255
  const int g = i >> 6;                 // 64-col group (wave-uniform)
  const int il = i & 63;
  float r[64];
  #pragma unroll
  for (int j = 0; j < 64; ++j) r[j] = (j == il) ? 1.0f : 0.0f;

  const int ubase = __builtin_amdgcn_readfirstlane(b * 4608 + 32 * g);
  #pragma unroll
  for (int l = 0; l < 21; ++l) {
    const int lb = LLB[l];
    const int m = 1 << lb;
    const float* ul = U + ubase + l * 128;
    #pragma unroll
    for (int kl = 0; kl < 32; ++kl) {
      const int p = ((kl >> lb) << (lb + 1)) | (kl & (m - 1));
      const int q = p + m;
      const float u = ul[kl];
      const float t  = r[p] - r[q];
      const float np = fmaf(u, t, r[q]);    // u*p + (1-u)*q
      const float nq = fmaf(-u, t, r[p]);   // u*q + (1-u)*p
      r[p] = np;
      r[q] = nq;
    }
  }
  float* op = staged + ((size_t)b * 256 + i) * 64;
  #pragma unroll
  for (int t = 0; t < 16; ++t)
    *(float4*)(op + 4 * t) =
        make_float4(r[4*t], r[4*t+1], r[4*t+2], r[4*t+3]);
}

// ---------------------------------------------------------------------------
// Kernel C: blocks 6..7 (layers 21..35).  Block = (b, rowgroup g of 64 rows).
// Thread = (chunk c of 64 cols, row rr), tid = c*64 + rr => each wave is one
// chunk, u addresses wave-uniform.  Two LDS exchanges (m=128, m=64) with
// lane-contiguous b128 pattern; final XOR-swizzled LDS transpose so global
// stores are 1KB lane-contiguous per wave (fixes 2.6x write amplification).
// ---------------------------------------------------------------------------
__global__ __launch_bounds__(256) void k_phase23(const float* __restrict__ U,
                                                 const float* __restrict__ staged,
                                                 float* __restrict__ out) {
  const int bg = blockIdx.x;
  const int b = bg >> 2;
  const int g = bg & 3;
  const int c  = threadIdx.x >> 6;      // chunk 0..3 (== wave id)
  const int rr = threadIdx.x & 63;      // row within group
  const int i = g * 64 + rr;
  __shared__ float4 ex4[4096];          // 64 KB, multi-purpose
  float y[64];

  const int ub = __builtin_amdgcn_readfirstlane(b * 4608);

  // ---- l=21: blk6, m=64.  Incoming support = cols [64g,64g+64); exactly one
  // chunk of each pair is nonzero, so new = staged * (u or 1-u), or 0.
  {
    const int ap = g >> 1;              // 128-region
    if ((c >> 1) == ap) {
      const float* u21 = U + ub + 21 * 128 + 64 * ap;
      const bool sm = ((c & 1) == (g & 1));   // my side == nonzero side
      const float* srp = staged + ((size_t)b * 256 + i) * 64;
      #pragma unroll
      for (int t = 0; t < 16; ++t) {
        const float4 s4 = *(const float4*)(srp + 4 * t);
        const float u0 = u21[4*t+0], u1 = u21[4*t+1];
        const float u2 = u21[4*t+2], u3 = u21[4*t+3];
        y[4*t+0] = s4.x * (sm ? u0 : 1.0f - u0);
        y[4*t+1] = s4.y * (sm ? u1 : 1.0f - u1);
        y[4*t+2] = s4.z * (sm ? u2 : 1.0f - u2);
        y[4*t+3] = s4.w * (sm ? u3 : 1.0f - u3);
      }
    } else {
      #pragma unroll
      for (int j = 0; j < 64; ++j) y[j] = 0.0f;
    }
  }

  const int cb = __builtin_amdgcn_readfirstlane(32 * c);

  // ---- blk6 in-register layers l=22..27 (m=32..1), pairs k in [32c,32c+32)
  #pragma unroll
  for (int l = 22; l < 28; ++l) {
    const int lb = LLB[l];
    const int m = 1 << lb;
    const float* ul = U + ub + l * 128 + cb;
    #pragma unroll
    for (int kl = 0; kl < 32; ++kl) {
      const int p = ((kl >> lb) << (lb + 1)) | (kl & (m - 1));
      const int q = p + m;
      const float u = ul[kl];
      const float t  = y[p] - y[q];
      const float np = fmaf(u, t, y[q]);
      const float nq = fmaf(-u, t, y[p]);
      y[p] = np;
      y[q] = nq;
    }
  }

  // ---- exchange 1 + l=28 (blk7, m=128): partner chunk c^2
  #pragma unroll
  for (int t = 0; t < 16; ++t)
    ex4[(c * 16 + t) * 64 + rr] =
        make_float4(y[4*t], y[4*t+1], y[4*t+2], y[4*t+3]);
  __syncthreads();
  {
    const int pc = c ^ 2;
    const float* u28 = U + ub + 28 * 128 + 64 * (c & 1);
    #pragma unroll
    for (int t = 0; t < 16; ++t) {
      const float4 p4 = ex4[(pc * 16 + t) * 64 + rr];
      const float u0 = u28[4*t+0], u1 = u28[4*t+1];
      const float u2 = u28[4*t+2], u3 = u28[4*t+3];
      y[4*t+0] = fmaf(u0, y[4*t+0] - p4.x, p4.x);
      y[4*t+1] = fmaf(u1, y[4*t+1] - p4.y, p4.y);
      y[4*t+2] = fmaf(u2, y[4*t+2] - p4.z, p4.z);
      y[4*t+3] = fmaf(u3, y[4*t+3] - p4.w, p4.w);
    }
  }
  __syncthreads();

  // ---- exchange 2 + l=29 (blk7, m=64): partner chunk c^1
  #pragma unroll
  for (int t = 0; t < 16; ++t)
    ex4[(c * 16 + t) * 64 + rr] =
        make_float4(y[4*t], y[4*t+1], y[4*t+2], y[4*t+3]);
  __syncthreads();
  {
    const int pc = c ^ 1;
    const float* u29 = U + ub + 29 * 128 + 64 * (c >> 1);
    #pragma unroll
    for (int t = 0; t < 16; ++t) {
      const float4 p4 = ex4[(pc * 16 + t) * 64 + rr];
      const float u0 = u29[4*t+0], u1 = u29[4*t+1];
      const float u2 = u29[4*t+2], u3 = u29[4*t+3];
      y[4*t+0] = fmaf(u0, y[4*t+0] - p4.x, p4.x);
      y[4*t+1] = fmaf(u1, y[4*t+1] - p4.y, p4.y);
      y[4*t+2] = fmaf(u2, y[4*t+2] - p4.z, p4.z);
      y[4*t+3] = fmaf(u3, y[4*t+3] - p4.w, p4.w);
    }
  }

  // ---- blk7 in-register layers l=30..35 (m=32..1)
  #pragma unroll
  for (int l = 30; l < 36; ++l) {
    const int lb = LLB[l];
    const int m = 1 << lb;
    const float* ul = U + ub + l * 128 + cb;
    #pragma unroll
    for (int kl = 0; kl < 32; ++kl) {
      const int p = ((kl >> lb) << (lb + 1)) | (kl & (m - 1));
      const int q = p + m;
      const float u = ul[kl];
      const float t  = y[p] - y[q];
      const float np = fmaf(u, t, y[q]);
      const float nq = fmaf(-u, t, y[p]);
      y[p] = np;
      y[q] = nq;
    }
  }

  // ---- XOR-swizzled LDS transpose -> coalesced 1KB/wave stores.
  // Block's output region is contiguous 64KB: rows [g*64, g*64+64) of batch b.
  __syncthreads();   // exchange-2 reads must finish before ex4 is overwritten
  #pragma unroll
  for (int t = 0; t < 16; ++t) {
    const int q = c * 16 + t;
    ex4[rr * 64 + (q ^ (rr & 7))] =
        make_float4(y[4*t], y[4*t+1], y[4*t+2], y[4*t+3]);
  }
  __syncthreads();
  {
    float4* out4 = (float4*)out + ((size_t)(b * 256 + g * 64)) * 64;
    const int tid = threadIdx.x;
    #pragma unroll
    for (int it = 0; it < 16; ++it) {
      const int fq = it * 256 + tid;     // float4 index within the 64KB block
      const int r = fq >> 6;
      const int q = fq & 63;
      const float4 v4 = ex4[r * 64 + (q ^ (r & 7))];
      __builtin_nontemporal_store(*(const vf4*)&v4, (vf4*)&out4[fq]);
    }
  }
}

// ---------------------------------------------------------------------------
extern "C" void kernel_launch(void* const* d_in, const int* in_sizes, int n_in,
                              void* d_out, int out_size, void* d_ws, size_t ws_size,
                              hipStream_t stream) {
  const float* vec = (const float*)d_in[0];   // vectors (512,256) f32
  float* out = (float*)d_out;                 // (512,256,256) f32
  float* U = (float*)d_ws;                    // 512*36*128 f32 = 9.4 MB
  float* staged = U + (size_t)512 * 4608;     // 512*256*64 f32 = 33.5 MB

  hipLaunchKernelGGL(k_ugen,    dim3(512),  dim3(128), 0, stream, vec, U);
  hipLaunchKernelGGL(k_phase1,  dim3(512),  dim3(256), 0, stream, U, staged);
  hipLaunchKernelGGL(k_phase23, dim3(2048), dim3(256), 0, stream, U, staged, out);
}